// Round 28
// baseline (128.881 us; speedup 1.0000x reference)
//
#include <hip/hip_runtime.h>
#include <hip/hip_bf16.h>

typedef __attribute__((ext_vector_type(8))) short short8;
typedef __attribute__((ext_vector_type(4))) float f32x4;
typedef __attribute__((ext_vector_type(4))) unsigned short u16x4;
typedef unsigned short u16;

#define Bn 8
#define Tn 2048
#define Cn 1024
#define Hn 64
#define Mrows (Bn * Tn)  // 16384

__device__ __forceinline__ u16 bfu(float f) {
    __hip_bfloat16 h = __float2bfloat16(f);
    union { __hip_bfloat16 h; u16 u; } c; c.h = h; return c.u;
}

__device__ __forceinline__ short8 cvt8(f32x4 a0, f32x4 a1) {
    short8 r;
    r[0] = (short)bfu(a0[0]); r[1] = (short)bfu(a0[1]);
    r[2] = (short)bfu(a0[2]); r[3] = (short)bfu(a0[3]);
    r[4] = (short)bfu(a1[0]); r[5] = (short)bfu(a1[1]);
    r[6] = (short)bfu(a1[2]); r[7] = (short)bfu(a1[3]);
    return r;
}

// W [1024][64] f32 x3 -> wtf fragment-linear bf16 (round-9 layout).
__global__ void convert_w3(const float* __restrict__ Wq, const float* __restrict__ Wk,
                           const float* __restrict__ Wv, u16* __restrict__ wtf, float qscale) {
    int widx = blockIdx.x * 256 + threadIdx.x;          // 0 .. 196607
    int mat = widx >> 16;
    int rem = widx & 65535;
    int k = rem >> 6, n = rem & 63;
    const float* W = mat == 0 ? Wq : (mat == 1 ? Wk : Wv);
    float s = mat == 0 ? qscale : 1.0f;
    int ct = mat * 4 + (n >> 4);
    int lane = ((k >> 3) & 3) * 16 + (n & 15);
    wtf[(size_t)(ct * 32 + (k >> 5)) * 512 + lane * 8 + (k & 7)] = bfu(W[rem] * s);
}

// x [16384][1024] f32 @ W -> q/k/v fragment-linear.
// ROUND-28: combines the two PROVEN ingredients:
//  (1) barrier-free single-wave blocks (R23: global queue never drains,
//      compiler pipelines freely, ~1024 independent waves)
//  (2) x read ONCE (R23's flaw was unit=tile x mat -> 3x x-reads, +10us HBM;
//      here one wave computes ALL 3 mats: acc[12], B = full wtf per unit,
//      393MB L2 = the proven-cheap R18 regime)
// Wave-private LDS A-staging (in-order within wave); R23-verified epilogue
// (coalesced q/k frag stores via ep re-stage; v u16x4 formula).
__global__ __launch_bounds__(64) void qkv_proj(const float* __restrict__ x,
                                               const u16* __restrict__ wtf,
                                               u16* __restrict__ qfl,
                                               u16* __restrict__ kfl,
                                               u16* __restrict__ vfl) {
    __shared__ u16 As[16][136];   // wave-private A tile (bf16)
    __shared__ u16 ep[16][68];    // epilogue re-stage (q/k)
    const int lane = threadIdx.x;
    const int l15 = lane & 15, lhi = lane >> 4;
    const int tile = (int)blockIdx.x;       // 0..1023
    const int row0 = tile * 16;

    const int srow = lane >> 4;             // 0..3 (row within 4-row group)
    const int scol = (lane & 15) * 8;       // f32 col 0..120

    f32x4 acc[12];
    #pragma unroll
    for (int nj = 0; nj < 12; ++nj) acc[nj] = f32x4{0.f, 0.f, 0.f, 0.f};

    #pragma unroll
    for (int ks = 0; ks < 8; ++ks) {
        // stage A: 4 row-groups, coalesced (f32 -> bf16 -> wave-private LDS)
        #pragma unroll
        for (int i = 0; i < 4; ++i) {
            const float* src = x + (size_t)(row0 + i * 4 + srow) * Cn + ks * 128 + scol;
            f32x4 a = *(const f32x4*)src;
            f32x4 b = *(const f32x4*)(src + 4);
            *(short8*)&As[i * 4 + srow][scol] = cvt8(a, b);
        }
        // in-order LDS within the wave: reads below see the writes above
        #pragma unroll
        for (int kc = 0; kc < 4; ++kc) {
            short8 af = *(const short8*)&As[l15][kc * 32 + lhi * 8];
            #pragma unroll
            for (int nj = 0; nj < 12; ++nj) {
                short8 bf = *(const short8*)(wtf + (size_t)(nj * 32 + ks * 4 + kc) * 512 + lane * 8);
                acc[nj] = __builtin_amdgcn_mfma_f32_16x16x32_bf16(af, bf, acc[nj], 0, 0, 0);
            }
        }
    }

    // ---- epilogue (R23-verified algebra) ----
    const int bI = row0 >> 11;              // batch
    const int tloc = row0 & 2047;
    // q (nj 0..3) and k (nj 4..7): re-stage -> two coalesced 1KB frag stores
    #pragma unroll
    for (int m = 0; m < 2; ++m) {
        #pragma unroll
        for (int njl = 0; njl < 4; ++njl)
            #pragma unroll
            for (int r = 0; r < 4; ++r)
                ep[lhi * 4 + r][njl * 16 + l15] = bfu(acc[m * 4 + njl][r]);
        u16* dst = (m == 0 ? qfl : kfl) + (size_t)bI * 131072;
        const int g = tloc >> 4;
        const int trow = lane & 15, lhid = lane >> 4;
        #pragma unroll
        for (int kcf = 0; kcf < 2; ++kcf) {
            short8 v8 = *(const short8*)&ep[trow][kcf * 32 + lhid * 8];
            *(short8*)(dst + ((size_t)(g * 2 + kcf)) * 512 + lane * 8) = v8;
        }
    }
    // v (nj 8..11): u16x4 formula (dt = nj-8)
    {
        const int growb = tloc + lhi * 4;
        const int kt64 = growb >> 6;
        const int tin = growb & 63;
        const int kcv = tin >> 5;
        const int lhiv = (tin & 31) >> 3;
        const int e0 = tin & 7;             // in {0,4}
        #pragma unroll
        for (int nj = 0; nj < 4; ++nj) {
            u16x4 pk;
            pk[0] = bfu(acc[8 + nj][0]); pk[1] = bfu(acc[8 + nj][1]);
            pk[2] = bfu(acc[8 + nj][2]); pk[3] = bfu(acc[8 + nj][3]);
            *(u16x4*)(vfl + ((size_t)((bI * 32 + kt64) * 4 + nj) * 2 + kcv) * 512
                          + (size_t)(lhiv * 16 + l15) * 8 + e0) = pk;
        }
    }
}

// Flash attention, causal. Block-level split-K, 8 waves per 16-row q-tile
// (round-17 verified, byte-identical; ~7us in-situ).
__global__ __launch_bounds__(512, 4) void attn_fwd(const u16* __restrict__ qfl,
                                                   const u16* __restrict__ kfl,
                                                   const u16* __restrict__ vfl,
                                                   float* __restrict__ out) {
    __shared__ float o_lds[8][16][68];
    __shared__ float ml_lds[8][2][16];
    __shared__ u16 pl[8][16][72];
    const int tid = threadIdx.x;
    const int lane = tid & 63;
    const int w = tid >> 6;           // 0..7
    const int l15 = lane & 15, lhi = lane >> 4;
    const int idx = (int)blockIdx.x;  // 0..1023
    const int qt = 127 - (idx >> 3);  // longest q-tiles dispatched first
    const int b = idx & 7;
    const int nkt = (qt >> 2) + 1;
    const int q0 = qt * 16;

    const u16* qb = qfl + (size_t)b * 131072;
    const u16* kb = kfl + (size_t)b * 131072;
    const u16* vb = vfl + (size_t)b * 131072;

    short8 qf[2];
    #pragma unroll
    for (int kc = 0; kc < 2; ++kc)
        qf[kc] = *(const short8*)(qb + ((size_t)(qt * 2 + kc) * 64 + lane) * 8);

    float m = -1e30f, lpart = 0.f;
    f32x4 o[4];
    for (int dt = 0; dt < 4; ++dt) o[dt] = f32x4{0.f, 0.f, 0.f, 0.f};

    for (int kbi = w; kbi < nkt; kbi += 8) {
        const int k0 = kbi * 64;
        short8 kf[2][4], vf[4][2];
        #pragma unroll
        for (int kc = 0; kc < 2; ++kc)
            #pragma unroll
            for (int kt = 0; kt < 4; ++kt)
                kf[kc][kt] = *(const short8*)(kb + ((size_t)((kbi * 4 + kt) * 2 + kc) * 64 + lane) * 8);
        #pragma unroll
        for (int dt = 0; dt < 4; ++dt)
            #pragma unroll
            for (int kc = 0; kc < 2; ++kc)
                vf[dt][kc] = *(const short8*)(vb + ((size_t)((kbi * 4 + dt) * 2 + kc) * 512 + lane * 8));

        f32x4 sacc[4];
        for (int kt = 0; kt < 4; ++kt) sacc[kt] = f32x4{0.f, 0.f, 0.f, 0.f};
        #pragma unroll
        for (int kc = 0; kc < 2; ++kc)
            #pragma unroll
            for (int kt = 0; kt < 4; ++kt)
                sacc[kt] = __builtin_amdgcn_mfma_f32_16x16x32_bf16(kf[kc][kt], qf[kc], sacc[kt], 0, 0, 0);

        if (kbi == nkt - 1) {             // diagonal: causal mask
            for (int kt = 0; kt < 4; ++kt)
                for (int r = 0; r < 4; ++r) {
                    int kg = k0 + kt * 16 + lhi * 4 + r;
                    if (kg > q0 + l15) sacc[kt][r] = -3.0e38f;
                }
        }
        f32x4 mx0, mx1;
        for (int e = 0; e < 4; ++e) {
            mx0[e] = fmaxf(sacc[0][e], sacc[1][e]);
            mx1[e] = fmaxf(sacc[2][e], sacc[3][e]);
        }
        float tmax = -3.0e38f;
        for (int e = 0; e < 4; ++e) tmax = fmaxf(tmax, fmaxf(mx0[e], mx1[e]));
        tmax = fmaxf(tmax, __shfl_xor(tmax, 16));
        tmax = fmaxf(tmax, __shfl_xor(tmax, 32));
        if (!__all(tmax <= m + 8.0f)) {   // defer-max (THR=8, log2 domain)
            float mnew = fmaxf(m, tmax);
            float corr = exp2f(m - mnew);
            m = mnew;
            lpart *= corr;
            for (int r = 0; r < 4; ++r) {
                float cr = __shfl(corr, lhi * 4 + r);
                for (int dt = 0; dt < 4; ++dt) o[dt][r] *= cr;
            }
        }
        float psum = 0.f;
        for (int kt = 0; kt < 4; ++kt)
            for (int r = 0; r < 4; ++r) {
                float p = exp2f(sacc[kt][r] - m);
                sacc[kt][r] = p;
                psum += p;
            }
        lpart += psum;
        for (int kt = 0; kt < 4; ++kt) {
            u16x4 pk;
            pk[0] = bfu(sacc[kt][0]); pk[1] = bfu(sacc[kt][1]);
            pk[2] = bfu(sacc[kt][2]); pk[3] = bfu(sacc[kt][3]);
            *(u16x4*)&pl[w][l15][kt * 16 + lhi * 4] = pk;
        }
        short8 pf[2];
        #pragma unroll
        for (int kc = 0; kc < 2; ++kc)
            pf[kc] = *(const short8*)&pl[w][l15][kc * 32 + lhi * 8];
        #pragma unroll
        for (int dt = 0; dt < 4; ++dt)
            #pragma unroll
            for (int kc = 0; kc < 2; ++kc)
                o[dt] = __builtin_amdgcn_mfma_f32_16x16x32_bf16(pf[kc], vf[dt][kc], o[dt], 0, 0, 0);
    }
    float lsum = lpart;
    lsum += __shfl_xor(lsum, 16);
    lsum += __shfl_xor(lsum, 32);

    for (int dt = 0; dt < 4; ++dt)
        for (int r = 0; r < 4; ++r)
            o_lds[w][lhi * 4 + r][dt * 16 + l15] = o[dt][r];
    if (lhi == 0) {
        ml_lds[w][0][l15] = m;
        ml_lds[w][1][l15] = lsum;
    }
    __syncthreads();

    float* ob = out + ((size_t)b * Tn + q0) * Hn;
    #pragma unroll
    for (int i = 0; i < 2; ++i) {
        const int e = tid + 512 * i;      // 0..1023
        const int row = e >> 6, d = e & 63;
        float M = -3.0e38f;
        #pragma unroll
        for (int ww = 0; ww < 8; ++ww) M = fmaxf(M, ml_lds[ww][0][row]);
        float L = 0.f, acc = 0.f;
        #pragma unroll
        for (int ww = 0; ww < 8; ++ww) {
            float wgt = exp2f(ml_lds[ww][0][row] - M);
            L += ml_lds[ww][1][row] * wgt;
            acc += o_lds[ww][row][d] * wgt;
        }
        ob[(size_t)row * Hn + d] = acc / L;
    }
}

extern "C" void kernel_launch(void* const* d_in, const int* in_sizes, int n_in,
                              void* d_out, int out_size, void* d_ws, size_t ws_size,
                              hipStream_t stream) {
    const float* x = (const float*)d_in[0];
    const float* Wq = (const float*)d_in[1];
    const float* Wk = (const float*)d_in[2];
    const float* Wv = (const float*)d_in[3];
    float* out = (float*)d_out;
    char* ws = (char*)d_ws;

    u16* wtf = (u16*)ws;                                   // 384 KB
    u16* qfl = (u16*)(ws + 196608 * 2);                    // 2 MB
    u16* kfl = qfl + (size_t)Bn * 131072;                  // 2 MB
    u16* vfl = kfl + (size_t)Bn * 131072;                  // 2 MB

    const float qscale = 0.04508422002778011f;  // C^-0.5 * log2(e)
    convert_w3<<<768, 256, 0, stream>>>(Wq, Wk, Wv, wtf, qscale);
    qkv_proj<<<1024, 64, 0, stream>>>(x, wtf, qfl, kfl, vfl);
    attn_fwd<<<1024, 512, 0, stream>>>(qfl, kfl, vfl, out);
}

// Round 29
// 43.777 us; speedup vs baseline: 2.9440x; 2.9440x over previous
//
#include <hip/hip_runtime.h>
#include <hip/hip_bf16.h>

typedef __attribute__((ext_vector_type(8))) short short8;
typedef __attribute__((ext_vector_type(4))) float f32x4;
typedef __attribute__((ext_vector_type(4))) unsigned short u16x4;
typedef unsigned short u16;

#define Bn 8
#define Tn 2048
#define Cn 1024
#define Hn 64
#define Mrows (Bn * Tn)  // 16384

#define BARRIER_KEEP_VMCNT() do { \
    asm volatile("s_waitcnt lgkmcnt(0)" ::: "memory"); \
    __builtin_amdgcn_s_barrier(); \
} while (0)

__device__ __forceinline__ u16 bfu(float f) {
    __hip_bfloat16 h = __float2bfloat16(f);
    union { __hip_bfloat16 h; u16 u; } c; c.h = h; return c.u;
}

__device__ __forceinline__ short8 cvt8(f32x4 a0, f32x4 a1) {
    short8 r;
    r[0] = (short)bfu(a0[0]); r[1] = (short)bfu(a0[1]);
    r[2] = (short)bfu(a0[2]); r[3] = (short)bfu(a0[3]);
    r[4] = (short)bfu(a1[0]); r[5] = (short)bfu(a1[1]);
    r[6] = (short)bfu(a1[2]); r[7] = (short)bfu(a1[3]);
    return r;
}

// W [1024][64] f32 x3 -> wtf fragment-linear bf16 (round-9 layout).
__global__ void convert_w3(const float* __restrict__ Wq, const float* __restrict__ Wk,
                           const float* __restrict__ Wv, u16* __restrict__ wtf, float qscale) {
    int widx = blockIdx.x * 256 + threadIdx.x;          // 0 .. 196607
    int mat = widx >> 16;
    int rem = widx & 65535;
    int k = rem >> 6, n = rem & 63;
    const float* W = mat == 0 ? Wq : (mat == 1 ? Wk : Wv);
    float s = mat == 0 ? qscale : 1.0f;
    int ct = mat * 4 + (n >> 4);
    int lane = ((k >> 3) & 3) * 16 + (n & 15);
    wtf[(size_t)(ct * 32 + (k >> 5)) * 512 + lane * 8 + (k & 7)] = bfu(W[rem] * s);
}

// x [16384][1024] f32 @ W -> q/k/v fragment-linear. ROUND-27 VERIFIED BEST
// (43.8us total): double-buffered NAMED B-register file breg[2][4][3]
// (96 VGPRs), K-loop fully unrolled; all 12 next-step B loads issue
// back-to-back at the top of each K-step -> in flight across the whole step.
// R28's acc[12] single-wave variant collapsed to 1 wave/SIMD (reverted).
__global__ __launch_bounds__(256, 2) void qkv_proj(const float* __restrict__ x,
                                                   const u16* __restrict__ wtf,
                                                   u16* __restrict__ qfl,
                                                   u16* __restrict__ kfl,
                                                   u16* __restrict__ vfl) {
    __shared__ u16 As[2][32][136];
    const int tid = threadIdx.x;
    const int lane = tid & 63;
    const int wn = tid >> 6;          // 0..3 -> 48-col slice (distinct per wave)
    const int l15 = lane & 15;
    const int lhi = lane >> 4;
    const int row0 = blockIdx.x * 32;

    const int arow = tid >> 3;        // 0..31
    const int ac0 = (tid & 7) * 16;   // f32 col base 0..112 (16 f32/thread)
    const float* asrc = x + (size_t)(row0 + arow) * Cn + ac0;
    const u16* wb = wtf + (size_t)(wn * 3) * 32 * 512 + lane * 8;

    f32x4 acc[2][3];
    #pragma unroll
    for (int mt = 0; mt < 2; ++mt)
        #pragma unroll
        for (int nj = 0; nj < 3; ++nj) acc[mt][nj] = f32x4{0.f, 0.f, 0.f, 0.f};

    short8 breg[2][4][3];

    // prologue: B(ks=0) -> breg[0]; x ks0 -> LDS buf0; x ks1 -> regs
    #pragma unroll
    for (int kc = 0; kc < 4; ++kc)
        #pragma unroll
        for (int nj = 0; nj < 3; ++nj)
            breg[0][kc][nj] = *(const short8*)(wb + (size_t)(nj * 32 + kc) * 512);
    f32x4 r0 = *(const f32x4*)(asrc);
    f32x4 r1 = *(const f32x4*)(asrc + 4);
    f32x4 r2 = *(const f32x4*)(asrc + 8);
    f32x4 r3 = *(const f32x4*)(asrc + 12);
    *(short8*)&As[0][arow][ac0]     = cvt8(r0, r1);
    *(short8*)&As[0][arow][ac0 + 8] = cvt8(r2, r3);
    r0 = *(const f32x4*)(asrc + 128);
    r1 = *(const f32x4*)(asrc + 132);
    r2 = *(const f32x4*)(asrc + 136);
    r3 = *(const f32x4*)(asrc + 140);
    BARRIER_KEEP_VMCNT();

    #pragma unroll
    for (int ks = 0; ks < 8; ++ks) {
        const int cur = ks & 1;       // compile-time under full unroll
        if (ks < 7) {
            // 1) issue ALL 12 next-step B loads first (fills the queue)
            #pragma unroll
            for (int kc = 0; kc < 4; ++kc)
                #pragma unroll
                for (int nj = 0; nj < 3; ++nj)
                    breg[cur ^ 1][kc][nj] =
                        *(const short8*)(wb + (size_t)(nj * 32 + (ks + 1) * 4 + kc) * 512);
            // 2) stage x (ks+1 data, loaded last step) -> LDS
            *(short8*)&As[cur ^ 1][arow][ac0]     = cvt8(r0, r1);
            *(short8*)&As[cur ^ 1][arow][ac0 + 8] = cvt8(r2, r3);
            // 3) prefetch x for ks+2
            if (ks < 6) {
                const float* nsrc = asrc + (size_t)(ks + 2) * 128;
                r0 = *(const f32x4*)(nsrc);
                r1 = *(const f32x4*)(nsrc + 4);
                r2 = *(const f32x4*)(nsrc + 8);
                r3 = *(const f32x4*)(nsrc + 12);
            }
        }
        // 4) MFMAs from As[cur] + breg[cur] (loaded one full K-step ago)
        #pragma unroll
        for (int kc = 0; kc < 4; ++kc) {
            short8 af0 = *(const short8*)&As[cur][l15][kc * 32 + lhi * 8];
            short8 af1 = *(const short8*)&As[cur][16 + l15][kc * 32 + lhi * 8];
            #pragma unroll
            for (int nj = 0; nj < 3; ++nj) {
                acc[0][nj] = __builtin_amdgcn_mfma_f32_16x16x32_bf16(af0, breg[cur][kc][nj], acc[0][nj], 0, 0, 0);
                acc[1][nj] = __builtin_amdgcn_mfma_f32_16x16x32_bf16(af1, breg[cur][kc][nj], acc[1][nj], 0, 0, 0);
            }
        }
        BARRIER_KEEP_VMCNT();
    }

    // epilogue: scatter into fragment-linear q/k/v (round-9 verified algebra)
    for (int mt = 0; mt < 2; ++mt) {
        const int growb = row0 + mt * 16 + lhi * 4;    // t = growb + r
        const int bI = growb >> 11;
        const int tloc = growb & 2047;
        for (int nj = 0; nj < 3; ++nj) {
            const int gcolb = wn * 48 + nj * 16;
            const int matid = gcolb >> 6;
            const int d0 = gcolb & 63;
            if (matid < 2) {
                u16* dst = matid == 0 ? qfl : kfl;
                const int g = tloc >> 4;
                const int lhid = ((d0 & 31) + l15) >> 3;
                const size_t base = ((size_t)(bI * 128 + g) * 2 + (d0 >> 5)) * 512
                                    + (size_t)lhid * 128 + (l15 & 7);
                for (int r = 0; r < 4; ++r)
                    dst[base + (size_t)(lhi * 4 + r) * 8] = bfu(acc[mt][nj][r]);
            } else {
                const int kt64 = tloc >> 6;
                const int tin = tloc & 63;
                const int kcv = tin >> 5;
                const int lhiv = (tin & 31) >> 3;
                const int e0 = tin & 7;
                const int dt = d0 >> 4;
                u16x4 pk;
                pk[0] = bfu(acc[mt][nj][0]); pk[1] = bfu(acc[mt][nj][1]);
                pk[2] = bfu(acc[mt][nj][2]); pk[3] = bfu(acc[mt][nj][3]);
                *(u16x4*)(vfl + ((size_t)((bI * 32 + kt64) * 4 + dt) * 2 + kcv) * 512
                              + (size_t)(lhiv * 16 + l15) * 8 + e0) = pk;
            }
        }
    }
}

// Flash attention, causal. Block-level split-K, 8 waves per 16-row q-tile
// (round-17 verified; ~7us in-situ).
__global__ __launch_bounds__(512, 4) void attn_fwd(const u16* __restrict__ qfl,
                                                   const u16* __restrict__ kfl,
                                                   const u16* __restrict__ vfl,
                                                   float* __restrict__ out) {
    __shared__ float o_lds[8][16][68];
    __shared__ float ml_lds[8][2][16];
    __shared__ u16 pl[8][16][72];
    const int tid = threadIdx.x;
    const int lane = tid & 63;
    const int w = tid >> 6;           // 0..7
    const int l15 = lane & 15, lhi = lane >> 4;
    const int idx = (int)blockIdx.x;  // 0..1023
    const int qt = 127 - (idx >> 3);  // longest q-tiles dispatched first
    const int b = idx & 7;
    const int nkt = (qt >> 2) + 1;
    const int q0 = qt * 16;

    const u16* qb = qfl + (size_t)b * 131072;
    const u16* kb = kfl + (size_t)b * 131072;
    const u16* vb = vfl + (size_t)b * 131072;

    short8 qf[2];
    #pragma unroll
    for (int kc = 0; kc < 2; ++kc)
        qf[kc] = *(const short8*)(qb + ((size_t)(qt * 2 + kc) * 64 + lane) * 8);

    float m = -1e30f, lpart = 0.f;
    f32x4 o[4];
    for (int dt = 0; dt < 4; ++dt) o[dt] = f32x4{0.f, 0.f, 0.f, 0.f};

    for (int kbi = w; kbi < nkt; kbi += 8) {
        const int k0 = kbi * 64;
        short8 kf[2][4], vf[4][2];
        #pragma unroll
        for (int kc = 0; kc < 2; ++kc)
            #pragma unroll
            for (int kt = 0; kt < 4; ++kt)
                kf[kc][kt] = *(const short8*)(kb + ((size_t)((kbi * 4 + kt) * 2 + kc) * 64 + lane) * 8);
        #pragma unroll
        for (int dt = 0; dt < 4; ++dt)
            #pragma unroll
            for (int kc = 0; kc < 2; ++kc)
                vf[dt][kc] = *(const short8*)(vb + ((size_t)((kbi * 4 + dt) * 2 + kc) * 512 + lane * 8));

        f32x4 sacc[4];
        for (int kt = 0; kt < 4; ++kt) sacc[kt] = f32x4{0.f, 0.f, 0.f, 0.f};
        #pragma unroll
        for (int kc = 0; kc < 2; ++kc)
            #pragma unroll
            for (int kt = 0; kt < 4; ++kt)
                sacc[kt] = __builtin_amdgcn_mfma_f32_16x16x32_bf16(kf[kc][kt], qf[kc], sacc[kt], 0, 0, 0);

        if (kbi == nkt - 1) {             // diagonal: causal mask
            for (int kt = 0; kt < 4; ++kt)
                for (int r = 0; r < 4; ++r) {
                    int kg = k0 + kt * 16 + lhi * 4 + r;
                    if (kg > q0 + l15) sacc[kt][r] = -3.0e38f;
                }
        }
        f32x4 mx0, mx1;
        for (int e = 0; e < 4; ++e) {
            mx0[e] = fmaxf(sacc[0][e], sacc[1][e]);
            mx1[e] = fmaxf(sacc[2][e], sacc[3][e]);
        }
        float tmax = -3.0e38f;
        for (int e = 0; e < 4; ++e) tmax = fmaxf(tmax, fmaxf(mx0[e], mx1[e]));
        tmax = fmaxf(tmax, __shfl_xor(tmax, 16));
        tmax = fmaxf(tmax, __shfl_xor(tmax, 32));
        if (!__all(tmax <= m + 8.0f)) {   // defer-max (THR=8, log2 domain)
            float mnew = fmaxf(m, tmax);
            float corr = exp2f(m - mnew);
            m = mnew;
            lpart *= corr;
            for (int r = 0; r < 4; ++r) {
                float cr = __shfl(corr, lhi * 4 + r);
                for (int dt = 0; dt < 4; ++dt) o[dt][r] *= cr;
            }
        }
        float psum = 0.f;
        for (int kt = 0; kt < 4; ++kt)
            for (int r = 0; r < 4; ++r) {
                float p = exp2f(sacc[kt][r] - m);
                sacc[kt][r] = p;
                psum += p;
            }
        lpart += psum;
        for (int kt = 0; kt < 4; ++kt) {
            u16x4 pk;
            pk[0] = bfu(sacc[kt][0]); pk[1] = bfu(sacc[kt][1]);
            pk[2] = bfu(sacc[kt][2]); pk[3] = bfu(sacc[kt][3]);
            *(u16x4*)&pl[w][l15][kt * 16 + lhi * 4] = pk;
        }
        short8 pf[2];
        #pragma unroll
        for (int kc = 0; kc < 2; ++kc)
            pf[kc] = *(const short8*)&pl[w][l15][kc * 32 + lhi * 8];
        #pragma unroll
        for (int dt = 0; dt < 4; ++dt)
            #pragma unroll
            for (int kc = 0; kc < 2; ++kc)
                o[dt] = __builtin_amdgcn_mfma_f32_16x16x32_bf16(pf[kc], vf[dt][kc], o[dt], 0, 0, 0);
    }
    float lsum = lpart;
    lsum += __shfl_xor(lsum, 16);
    lsum += __shfl_xor(lsum, 32);

    for (int dt = 0; dt < 4; ++dt)
        for (int r = 0; r < 4; ++r)
            o_lds[w][lhi * 4 + r][dt * 16 + l15] = o[dt][r];
    if (lhi == 0) {
        ml_lds[w][0][l15] = m;
        ml_lds[w][1][l15] = lsum;
    }
    __syncthreads();

    float* ob = out + ((size_t)b * Tn + q0) * Hn;
    #pragma unroll
    for (int i = 0; i < 2; ++i) {
        const int e = tid + 512 * i;      // 0..1023
        const int row = e >> 6, d = e & 63;
        float M = -3.0e38f;
        #pragma unroll
        for (int ww = 0; ww < 8; ++ww) M = fmaxf(M, ml_lds[ww][0][row]);
        float L = 0.f, acc = 0.f;
        #pragma unroll
        for (int ww = 0; ww < 8; ++ww) {
            float wgt = exp2f(ml_lds[ww][0][row] - M);
            L += ml_lds[ww][1][row] * wgt;
            acc += o_lds[ww][row][d] * wgt;
        }
        ob[(size_t)row * Hn + d] = acc / L;
    }
}

extern "C" void kernel_launch(void* const* d_in, const int* in_sizes, int n_in,
                              void* d_out, int out_size, void* d_ws, size_t ws_size,
                              hipStream_t stream) {
    const float* x = (const float*)d_in[0];
    const float* Wq = (const float*)d_in[1];
    const float* Wk = (const float*)d_in[2];
    const float* Wv = (const float*)d_in[3];
    float* out = (float*)d_out;
    char* ws = (char*)d_ws;

    u16* wtf = (u16*)ws;                                   // 384 KB
    u16* qfl = (u16*)(ws + 196608 * 2);                    // 2 MB
    u16* kfl = qfl + (size_t)Bn * 131072;                  // 2 MB
    u16* vfl = kfl + (size_t)Bn * 131072;                  // 2 MB

    const float qscale = 0.04508422002778011f;  // C^-0.5 * log2(e)
    convert_w3<<<768, 256, 0, stream>>>(Wq, Wk, Wv, wtf, qscale);
    qkv_proj<<<Mrows / 32, 256, 0, stream>>>(x, wtf, qfl, kfl, vfl);
    attn_fwd<<<1024, 512, 0, stream>>>(qfl, kfl, vfl, out);
}